// Round 3
// baseline (3249.360 us; speedup 1.0000x reference)
//
#include <hip/hip_runtime.h>
#include <hip/hip_bf16.h>

// MultiAttentionHead: B=2, T=2048, E=1024, H=16, D=64
// Inputs (fp32): x[B,T,E], Wq[H,E,D], Wk[H,E,D], Wv[H,E,D], Wo[E,E]
// Output (fp32): combined @ Wo + x   [B,T,E]
//
// ws layout (fp16 bits): q[4M] | k[4M] | v[4M] | comb[4M] = 32 MB total.

#define B_ 2
#define T_ 2048
#define E_ 1024
#define H_ 16
#define D_ 64

__device__ __forceinline__ float h2f(unsigned short s) {
  _Float16 h;
  __builtin_memcpy(&h, &s, 2);
  return (float)h;
}

__device__ __forceinline__ unsigned short f2h(float f) {
  _Float16 h = (_Float16)f;
  unsigned short s;
  __builtin_memcpy(&s, &h, 2);
  return s;
}

// ---------------------------------------------------------------------------
// Kernel 1: q/k/v projections.  grid=(B*T/64, H, 3), block=256.
// Each block: 64 tokens x 64 dims for one head, one of {q,k,v}. fp16 out.
// ---------------------------------------------------------------------------
__global__ __launch_bounds__(256) void qkv_kernel(
    const float* __restrict__ x,
    const float* __restrict__ Wq,
    const float* __restrict__ Wk,
    const float* __restrict__ Wv,
    unsigned short* __restrict__ qo, unsigned short* __restrict__ ko,
    unsigned short* __restrict__ vo)
{
  __shared__ float xs[32][68];  // [kk][row]  (transposed A tile)
  __shared__ float ws[32][68];  // [kk][col]

  const int bt0   = blockIdx.x * 64;
  const int h     = blockIdx.y;
  const int which = blockIdx.z;
  const float* W = ((which == 0) ? Wq : (which == 1) ? Wk : Wv) + (size_t)h * E_ * D_;
  unsigned short* outp = (which == 0) ? qo : (which == 1) ? ko : vo;

  const unsigned tid = threadIdx.x;
  const int ty = tid >> 4, tx = tid & 15;      // 16x16 threads, each 4x4 outputs
  const int xr = tid >> 2, xc = (tid & 3) * 8; // x-tile load: 64 rows x 32 cols
  const int wr = tid >> 3, wc = (tid & 7) * 8; // W-tile load: 32 rows x 64 cols

  float acc[4][4] = {};

  for (int e0 = 0; e0 < E_; e0 += 32) {
    const float4* xsrc = (const float4*)(x + (size_t)(bt0 + xr) * E_ + e0 + xc);
    const float4 x0 = xsrc[0], x1 = xsrc[1];
    xs[xc + 0][xr] = x0.x; xs[xc + 1][xr] = x0.y; xs[xc + 2][xr] = x0.z; xs[xc + 3][xr] = x0.w;
    xs[xc + 4][xr] = x1.x; xs[xc + 5][xr] = x1.y; xs[xc + 6][xr] = x1.z; xs[xc + 7][xr] = x1.w;

    const float4* wsrc = (const float4*)(W + (size_t)(e0 + wr) * D_ + wc);
    *(float4*)&ws[wr][wc]     = wsrc[0];
    *(float4*)&ws[wr][wc + 4] = wsrc[1];
    __syncthreads();

#pragma unroll
    for (int kk = 0; kk < 32; kk++) {
      const float4 a  = *(const float4*)&xs[kk][ty * 4];
      const float4 w4 = *(const float4*)&ws[kk][tx * 4];
      const float av[4] = {a.x, a.y, a.z, a.w};
      const float wv[4] = {w4.x, w4.y, w4.z, w4.w};
#pragma unroll
      for (int i = 0; i < 4; i++)
#pragma unroll
        for (int j = 0; j < 4; j++) acc[i][j] += av[i] * wv[j];
    }
    __syncthreads();
  }

#pragma unroll
  for (int i = 0; i < 4; i++) {
    const int bt = bt0 + ty * 4 + i;
    const int b  = bt >> 11;        // / T_
    const int t  = bt & (T_ - 1);
    ushort4 pk;
    pk.x = f2h(acc[i][0]); pk.y = f2h(acc[i][1]);
    pk.z = f2h(acc[i][2]); pk.w = f2h(acc[i][3]);
    *(ushort4*)(outp + ((size_t)(b * H_ + h) * T_ + t) * D_ + tx * 4) = pk;
  }
}

// ---------------------------------------------------------------------------
// Kernel 2: flash attention, fp32 compute over fp16 q/k/v.
// grid=(T/64, H, B), block=64 (one wave). Lane owns one Q row.
// K/V rows are wave-uniform loads; per-lane score buffer in LDS.
// ---------------------------------------------------------------------------
__global__ __launch_bounds__(64) void attn_kernel(
    const unsigned short* __restrict__ q, const unsigned short* __restrict__ k,
    const unsigned short* __restrict__ v, unsigned short* __restrict__ comb)
{
  __shared__ float Ss[32][64];  // [j][lane]

  const int qt = blockIdx.x, h = blockIdx.y, b = blockIdx.z;
  const int lane = threadIdx.x;
  const size_t bh = (size_t)(b * H_ + h);
  const int t = qt * 64 + lane;

  const unsigned short* qp = q + (bh * T_ + t) * (size_t)D_;
  float qr[64];
  const uint4* q4 = (const uint4*)qp;
#pragma unroll
  for (int c = 0; c < 8; c++) {
    uint4 raw = q4[c];
    const unsigned short* s8 = (const unsigned short*)&raw;
#pragma unroll
    for (int i = 0; i < 8; i++) qr[c * 8 + i] = h2f(s8[i]);
  }

  float o[64];
#pragma unroll
  for (int d = 0; d < 64; d++) o[d] = 0.f;
  float m = -1e30f, l = 0.f;

  const unsigned short* kb = k + bh * (size_t)(T_ * D_);
  const unsigned short* vb = v + bh * (size_t)(T_ * D_);

  for (int kt = 0; kt < T_ / 32; kt++) {
    // ---- scores for 32 keys ----
    float mt = -1e30f;
#pragma unroll 4
    for (int j = 0; j < 32; j++) {
      const uint4* kr = (const uint4*)(kb + (size_t)(kt * 32 + j) * D_);
      float a0 = 0.f, a1 = 0.f, a2 = 0.f, a3 = 0.f;
#pragma unroll
      for (int c = 0; c < 8; c++) {
        uint4 raw = kr[c];  // wave-uniform
        const unsigned short* s8 = (const unsigned short*)&raw;
        a0 += qr[c * 8 + 0] * h2f(s8[0]);
        a1 += qr[c * 8 + 1] * h2f(s8[1]);
        a2 += qr[c * 8 + 2] * h2f(s8[2]);
        a3 += qr[c * 8 + 3] * h2f(s8[3]);
        a0 += qr[c * 8 + 4] * h2f(s8[4]);
        a1 += qr[c * 8 + 5] * h2f(s8[5]);
        a2 += qr[c * 8 + 6] * h2f(s8[6]);
        a3 += qr[c * 8 + 7] * h2f(s8[7]);
      }
      const float sj = (a0 + a1 + a2 + a3) * 0.125f;  // 1/sqrt(64)
      Ss[j][lane] = sj;
      mt = fmaxf(mt, sj);
    }

    // ---- online softmax update ----
    const float mnew  = fmaxf(m, mt);
    const float alpha = __expf(m - mnew);
    l *= alpha;
#pragma unroll
    for (int d = 0; d < 64; d++) o[d] *= alpha;

#pragma unroll 4
    for (int j = 0; j < 32; j++) {
      const float p = __expf(Ss[j][lane] - mnew);
      l += p;
      const uint4* vr = (const uint4*)(vb + (size_t)(kt * 32 + j) * D_);
#pragma unroll
      for (int c = 0; c < 8; c++) {
        uint4 raw = vr[c];  // wave-uniform
        const unsigned short* s8 = (const unsigned short*)&raw;
#pragma unroll
        for (int i = 0; i < 8; i++) o[c * 8 + i] += p * h2f(s8[i]);
      }
    }
    m = mnew;
  }

  const float inv = 1.f / l;
  unsigned short* dst = comb + ((size_t)b * T_ + t) * E_ + h * D_;
#pragma unroll
  for (int d4 = 0; d4 < 16; d4++) {
    ushort4 pk;
    pk.x = f2h(o[4 * d4 + 0] * inv);
    pk.y = f2h(o[4 * d4 + 1] * inv);
    pk.z = f2h(o[4 * d4 + 2] * inv);
    pk.w = f2h(o[4 * d4 + 3] * inv);
    ((ushort4*)dst)[d4] = pk;
  }
}

// ---------------------------------------------------------------------------
// Kernel 3: out = comb @ Wo + x.  grid=(B*T/64, E/64), block=256.
// comb fp16 bits; Wo/x fp32; out fp32.
// ---------------------------------------------------------------------------
__global__ __launch_bounds__(256) void out_kernel(
    const unsigned short* __restrict__ comb, const float* __restrict__ Wo,
    const float* __restrict__ x, float* __restrict__ out)
{
  __shared__ float cs[32][68];  // [kk][row]
  __shared__ float ws[32][68];  // [kk][col]

  const int n0 = blockIdx.x * 64;
  const int j0 = blockIdx.y * 64;
  const unsigned tid = threadIdx.x;
  const int ty = tid >> 4, tx = tid & 15;
  const int ar = tid >> 2, ac = (tid & 3) * 8;
  const int wr = tid >> 3, wc = (tid & 7) * 8;

  float acc[4][4] = {};

  for (int e0 = 0; e0 < E_; e0 += 32) {
    uint4 craw = *(const uint4*)(comb + (size_t)(n0 + ar) * E_ + e0 + ac);  // 8 fp16
    const unsigned short* c8 = (const unsigned short*)&craw;
#pragma unroll
    for (int i = 0; i < 8; i++) cs[ac + i][ar] = h2f(c8[i]);

    const float4* wsrc = (const float4*)(Wo + (size_t)(e0 + wr) * E_ + j0 + wc);
    *(float4*)&ws[wr][wc]     = wsrc[0];
    *(float4*)&ws[wr][wc + 4] = wsrc[1];
    __syncthreads();

#pragma unroll
    for (int kk = 0; kk < 32; kk++) {
      const float4 a  = *(const float4*)&cs[kk][ty * 4];
      const float4 w4 = *(const float4*)&ws[kk][tx * 4];
      const float av[4] = {a.x, a.y, a.z, a.w};
      const float wv[4] = {w4.x, w4.y, w4.z, w4.w};
#pragma unroll
      for (int i = 0; i < 4; i++)
#pragma unroll
        for (int j = 0; j < 4; j++) acc[i][j] += av[i] * wv[j];
    }
    __syncthreads();
  }

#pragma unroll
  for (int i = 0; i < 4; i++) {
    const int n = n0 + ty * 4 + i;
    const float4 xr4 = *(const float4*)(x + (size_t)n * E_ + j0 + tx * 4);
    float4 f = make_float4(acc[i][0] + xr4.x, acc[i][1] + xr4.y,
                           acc[i][2] + xr4.z, acc[i][3] + xr4.w);
    *(float4*)(out + (size_t)n * E_ + j0 + tx * 4) = f;
  }
}

// ---------------------------------------------------------------------------
extern "C" void kernel_launch(void* const* d_in, const int* in_sizes, int n_in,
                              void* d_out, int out_size, void* d_ws, size_t ws_size,
                              hipStream_t stream) {
  (void)in_sizes; (void)n_in; (void)out_size; (void)ws_size;

  const float* x  = (const float*)d_in[0];
  const float* Wq = (const float*)d_in[1];
  const float* Wk = (const float*)d_in[2];
  const float* Wv = (const float*)d_in[3];
  const float* Wo = (const float*)d_in[4];
  float* out = (float*)d_out;

  const size_t N = (size_t)B_ * H_ * T_ * D_;  // 4,194,304 elements
  unsigned short* qh   = (unsigned short*)d_ws;      // fp16 bits, 8 MB
  unsigned short* kh   = qh + N;                     // 8 MB
  unsigned short* vh   = kh + N;                     // 8 MB
  unsigned short* comb = vh + N;                     // 8 MB  (total 32 MB)

  dim3 g1(B_ * T_ / 64, H_, 3);
  qkv_kernel<<<g1, dim3(256), 0, stream>>>(x, Wq, Wk, Wv, qh, kh, vh);

  dim3 g2(T_ / 64, H_, B_);
  attn_kernel<<<g2, dim3(64), 0, stream>>>(qh, kh, vh, comb);

  dim3 g3(B_ * T_ / 64, E_ / 64);
  out_kernel<<<g3, dim3(256), 0, stream>>>(comb, Wo, x, out);
}

// Round 4
// 828.881 us; speedup vs baseline: 3.9202x; 3.9202x over previous
//
#include <hip/hip_runtime.h>
#include <hip/hip_bf16.h>

// MultiAttentionHead: B=2, T=2048, E=1024, H=16, D=64
// Inputs (fp32): x[B,T,E], Wq[H,E,D], Wk[H,E,D], Wv[H,E,D], Wo[E,E]
// Output (fp32): combined @ Wo + x   [B,T,E]
//
// ws layout (fp16 bits): q[4M] | k[4M] | vt[4M] | comb[4M] = 32 MB.
// q,k row-major [bh][t][d]; vt TRANSPOSED [bh][d][t] for MFMA B-frags.

#define B_ 2
#define T_ 2048
#define E_ 1024
#define H_ 16
#define D_ 64

typedef _Float16 h8 __attribute__((ext_vector_type(8)));
typedef float f32x4 __attribute__((ext_vector_type(4)));

union U4 { uint4 u; h8 h; };

__device__ __forceinline__ float h2f(unsigned short s) {
  _Float16 h;
  __builtin_memcpy(&h, &s, 2);
  return (float)h;
}

__device__ __forceinline__ unsigned short f2h(float f) {
  _Float16 h = (_Float16)f;
  unsigned short s;
  __builtin_memcpy(&s, &h, 2);
  return s;
}

// ---------------------------------------------------------------------------
// Kernel 1: q/k/v projections.  grid=(B*T/64, H, 3), block=256.
// q,k written row-major [t][d]; v written TRANSPOSED [d][t].
// ---------------------------------------------------------------------------
__global__ __launch_bounds__(256) void qkv_kernel(
    const float* __restrict__ x,
    const float* __restrict__ Wq,
    const float* __restrict__ Wk,
    const float* __restrict__ Wv,
    unsigned short* __restrict__ qo, unsigned short* __restrict__ ko,
    unsigned short* __restrict__ vo)
{
  __shared__ float xs[32][68];  // [kk][row]  (transposed A tile)
  __shared__ float ws[32][68];  // [kk][col]

  const int bt0   = blockIdx.x * 64;
  const int h     = blockIdx.y;
  const int which = blockIdx.z;
  const float* W = ((which == 0) ? Wq : (which == 1) ? Wk : Wv) + (size_t)h * E_ * D_;
  unsigned short* outp = (which == 0) ? qo : (which == 1) ? ko : vo;

  const unsigned tid = threadIdx.x;
  const int ty = tid >> 4, tx = tid & 15;      // 16x16 threads, each 4x4 outputs
  const int xr = tid >> 2, xc = (tid & 3) * 8; // x-tile load: 64 rows x 32 cols
  const int wr = tid >> 3, wc = (tid & 7) * 8; // W-tile load: 32 rows x 64 cols

  float acc[4][4] = {};

  for (int e0 = 0; e0 < E_; e0 += 32) {
    const float4* xsrc = (const float4*)(x + (size_t)(bt0 + xr) * E_ + e0 + xc);
    const float4 x0 = xsrc[0], x1 = xsrc[1];
    xs[xc + 0][xr] = x0.x; xs[xc + 1][xr] = x0.y; xs[xc + 2][xr] = x0.z; xs[xc + 3][xr] = x0.w;
    xs[xc + 4][xr] = x1.x; xs[xc + 5][xr] = x1.y; xs[xc + 6][xr] = x1.z; xs[xc + 7][xr] = x1.w;

    const float4* wsrc = (const float4*)(W + (size_t)(e0 + wr) * D_ + wc);
    *(float4*)&ws[wr][wc]     = wsrc[0];
    *(float4*)&ws[wr][wc + 4] = wsrc[1];
    __syncthreads();

#pragma unroll
    for (int kk = 0; kk < 32; kk++) {
      const float4 a  = *(const float4*)&xs[kk][ty * 4];
      const float4 w4 = *(const float4*)&ws[kk][tx * 4];
      const float av[4] = {a.x, a.y, a.z, a.w};
      const float wv[4] = {w4.x, w4.y, w4.z, w4.w};
#pragma unroll
      for (int i = 0; i < 4; i++)
#pragma unroll
        for (int j = 0; j < 4; j++) acc[i][j] += av[i] * wv[j];
    }
    __syncthreads();
  }

  const int b0 = bt0 >> 11;        // batch (tiles never straddle b; T%64==0)
  const int t0 = bt0 & (T_ - 1);

  if (which == 2) {
    // transposed store: vt[((b*H+h)*D + d)*T + t], pack 4 tokens along t
#pragma unroll
    for (int j = 0; j < 4; j++) {
      ushort4 pk;
      pk.x = f2h(acc[0][j]); pk.y = f2h(acc[1][j]);
      pk.z = f2h(acc[2][j]); pk.w = f2h(acc[3][j]);
      *(ushort4*)(outp + ((size_t)(b0 * H_ + h) * D_ + tx * 4 + j) * T_ + t0 + ty * 4) = pk;
    }
  } else {
#pragma unroll
    for (int i = 0; i < 4; i++) {
      ushort4 pk;
      pk.x = f2h(acc[i][0]); pk.y = f2h(acc[i][1]);
      pk.z = f2h(acc[i][2]); pk.w = f2h(acc[i][3]);
      *(ushort4*)(outp + ((size_t)(b0 * H_ + h) * T_ + t0 + ty * 4 + i) * D_ + tx * 4) = pk;
    }
  }
}

// ---------------------------------------------------------------------------
// Kernel 2: MFMA flash attention.  grid=(T/64, H, B), block=256 (4 waves).
// Wave = 16 Q-rows. Per 32-key iter: S = 4x mfma_16x16x32_f16 (2 col-tiles
// x 2 D-halves), online softmax (shfl_xor row reduce), P via LDS
// (C-layout -> A-layout), PV = 4x mfma into 16x64 O accumulator.
// MFMA layouts (guide §3, m89/m118/m120): A[m=lane&15][k=quad*8+j],
// B[k=quad*8+j][n=lane&15], C/D[row=quad*4+reg][col=lane&15].
// ---------------------------------------------------------------------------
__global__ __launch_bounds__(256) void attn_kernel(
    const unsigned short* __restrict__ q, const unsigned short* __restrict__ k,
    const unsigned short* __restrict__ vt, unsigned short* __restrict__ comb)
{
  __shared__ unsigned short Pl[4][16 * 40];  // per-wave P tile, row stride 40 (80 B, 16B-aligned)

  const int w    = threadIdx.x >> 6;
  const int lane = threadIdx.x & 63;
  const int m16  = lane & 15;
  const int quad = lane >> 4;
  const int h = blockIdx.y, b = blockIdx.z;
  const size_t bh = (size_t)(b * H_ + h);
  const int q0 = blockIdx.x * 64 + w * 16;

  // preload Q A-frags (two K=32 halves of D=64)
  U4 aQ0, aQ1;
  {
    const unsigned short* qrow = q + (bh * T_ + q0 + m16) * (size_t)D_;
    aQ0.u = *(const uint4*)(qrow + quad * 8);
    aQ1.u = *(const uint4*)(qrow + 32 + quad * 8);
  }

  f32x4 o0 = {0.f, 0.f, 0.f, 0.f}, o1 = o0, o2 = o0, o3 = o0;
  float mrow[4] = {-1e30f, -1e30f, -1e30f, -1e30f};
  float lrow[4] = {0.f, 0.f, 0.f, 0.f};

  const unsigned short* kb  = k  + bh * (size_t)(T_ * D_);
  const unsigned short* vtb = vt + bh * (size_t)(D_ * T_);
  unsigned short* Pw = &Pl[w][0];

  for (int kt = 0; kt < T_; kt += 32) {
    // ---- K B-frags: 2 key-col tiles x 2 D-halves ----
    const unsigned short* kr0 = kb + (size_t)(kt + m16) * D_ + quad * 8;
    const unsigned short* kr1 = kb + (size_t)(kt + 16 + m16) * D_ + quad * 8;
    U4 b00, b01, b10, b11;
    b00.u = *(const uint4*)(kr0);
    b01.u = *(const uint4*)(kr0 + 32);
    b10.u = *(const uint4*)(kr1);
    b11.u = *(const uint4*)(kr1 + 32);

    // ---- V B-frags (issued early; used after softmax) ----
    U4 v0, v1, v2, v3;
    v0.u = *(const uint4*)(vtb + (size_t)(m16)      * T_ + kt + quad * 8);
    v1.u = *(const uint4*)(vtb + (size_t)(16 + m16) * T_ + kt + quad * 8);
    v2.u = *(const uint4*)(vtb + (size_t)(32 + m16) * T_ + kt + quad * 8);
    v3.u = *(const uint4*)(vtb + (size_t)(48 + m16) * T_ + kt + quad * 8);

    f32x4 s0 = {0.f, 0.f, 0.f, 0.f}, s1 = s0;
    s0 = __builtin_amdgcn_mfma_f32_16x16x32_f16(aQ0.h, b00.h, s0, 0, 0, 0);
    s0 = __builtin_amdgcn_mfma_f32_16x16x32_f16(aQ1.h, b01.h, s0, 0, 0, 0);
    s1 = __builtin_amdgcn_mfma_f32_16x16x32_f16(aQ0.h, b10.h, s1, 0, 0, 0);
    s1 = __builtin_amdgcn_mfma_f32_16x16x32_f16(aQ1.h, b11.h, s1, 0, 0, 0);

    // ---- online softmax per row (row = quad*4 + r) ----
    float al[4];
#pragma unroll
    for (int r = 0; r < 4; r++) {
      const float sa = s0[r] * 0.125f;   // 1/sqrt(64)
      const float sb = s1[r] * 0.125f;
      float mt = fmaxf(sa, sb);
      mt = fmaxf(mt, __shfl_xor(mt, 1));
      mt = fmaxf(mt, __shfl_xor(mt, 2));
      mt = fmaxf(mt, __shfl_xor(mt, 4));
      mt = fmaxf(mt, __shfl_xor(mt, 8));
      const float mn = fmaxf(mrow[r], mt);
      const float a  = __expf(mrow[r] - mn);
      const float p0 = __expf(sa - mn);
      const float p1 = __expf(sb - mn);
      float rs = p0 + p1;
      rs += __shfl_xor(rs, 1);
      rs += __shfl_xor(rs, 2);
      rs += __shfl_xor(rs, 4);
      rs += __shfl_xor(rs, 8);
      lrow[r] = lrow[r] * a + rs;
      mrow[r] = mn;
      al[r] = a;
      Pw[(quad * 4 + r) * 40 + m16]      = f2h(p0);
      Pw[(quad * 4 + r) * 40 + 16 + m16] = f2h(p1);
    }

#pragma unroll
    for (int r = 0; r < 4; r++) {
      o0[r] *= al[r]; o1[r] *= al[r]; o2[r] *= al[r]; o3[r] *= al[r];
    }

    // ---- P: C-layout -> A-layout via per-wave LDS (same-wave DS is in-order) ----
    U4 aP;
    aP.u = *(const uint4*)(Pw + m16 * 40 + quad * 8);

    o0 = __builtin_amdgcn_mfma_f32_16x16x32_f16(aP.h, v0.h, o0, 0, 0, 0);
    o1 = __builtin_amdgcn_mfma_f32_16x16x32_f16(aP.h, v1.h, o1, 0, 0, 0);
    o2 = __builtin_amdgcn_mfma_f32_16x16x32_f16(aP.h, v2.h, o2, 0, 0, 0);
    o3 = __builtin_amdgcn_mfma_f32_16x16x32_f16(aP.h, v3.h, o3, 0, 0, 0);
  }

  // ---- epilogue: O /= l, store fp16 to comb[b][t][h*64 + d] ----
#pragma unroll
  for (int r = 0; r < 4; r++) {
    const float inv = 1.f / lrow[r];
    const int t = q0 + quad * 4 + r;
    unsigned short* dst = comb + ((size_t)b * T_ + t) * E_ + h * D_;
    dst[m16]      = f2h(o0[r] * inv);
    dst[16 + m16] = f2h(o1[r] * inv);
    dst[32 + m16] = f2h(o2[r] * inv);
    dst[48 + m16] = f2h(o3[r] * inv);
  }
}

// ---------------------------------------------------------------------------
// Kernel 3: out = comb @ Wo + x.  grid=(B*T/64, E/64), block=256.
// ---------------------------------------------------------------------------
__global__ __launch_bounds__(256) void out_kernel(
    const unsigned short* __restrict__ comb, const float* __restrict__ Wo,
    const float* __restrict__ x, float* __restrict__ out)
{
  __shared__ float cs[32][68];  // [kk][row]
  __shared__ float ws[32][68];  // [kk][col]

  const int n0 = blockIdx.x * 64;
  const int j0 = blockIdx.y * 64;
  const unsigned tid = threadIdx.x;
  const int ty = tid >> 4, tx = tid & 15;
  const int ar = tid >> 2, ac = (tid & 3) * 8;
  const int wr = tid >> 3, wc = (tid & 7) * 8;

  float acc[4][4] = {};

  for (int e0 = 0; e0 < E_; e0 += 32) {
    uint4 craw = *(const uint4*)(comb + (size_t)(n0 + ar) * E_ + e0 + ac);  // 8 fp16
    const unsigned short* c8 = (const unsigned short*)&craw;
#pragma unroll
    for (int i = 0; i < 8; i++) cs[ac + i][ar] = h2f(c8[i]);

    const float4* wsrc = (const float4*)(Wo + (size_t)(e0 + wr) * E_ + j0 + wc);
    *(float4*)&ws[wr][wc]     = wsrc[0];
    *(float4*)&ws[wr][wc + 4] = wsrc[1];
    __syncthreads();

#pragma unroll
    for (int kk = 0; kk < 32; kk++) {
      const float4 a  = *(const float4*)&cs[kk][ty * 4];
      const float4 w4 = *(const float4*)&ws[kk][tx * 4];
      const float av[4] = {a.x, a.y, a.z, a.w};
      const float wv[4] = {w4.x, w4.y, w4.z, w4.w};
#pragma unroll
      for (int i = 0; i < 4; i++)
#pragma unroll
        for (int j = 0; j < 4; j++) acc[i][j] += av[i] * wv[j];
    }
    __syncthreads();
  }

#pragma unroll
  for (int i = 0; i < 4; i++) {
    const int n = n0 + ty * 4 + i;
    const float4 xr4 = *(const float4*)(x + (size_t)n * E_ + j0 + tx * 4);
    float4 f = make_float4(acc[i][0] + xr4.x, acc[i][1] + xr4.y,
                           acc[i][2] + xr4.z, acc[i][3] + xr4.w);
    *(float4*)(out + (size_t)n * E_ + j0 + tx * 4) = f;
  }
}

// ---------------------------------------------------------------------------
extern "C" void kernel_launch(void* const* d_in, const int* in_sizes, int n_in,
                              void* d_out, int out_size, void* d_ws, size_t ws_size,
                              hipStream_t stream) {
  (void)in_sizes; (void)n_in; (void)out_size; (void)ws_size;

  const float* x  = (const float*)d_in[0];
  const float* Wq = (const float*)d_in[1];
  const float* Wk = (const float*)d_in[2];
  const float* Wv = (const float*)d_in[3];
  const float* Wo = (const float*)d_in[4];
  float* out = (float*)d_out;

  const size_t N = (size_t)B_ * H_ * T_ * D_;  // 4,194,304 elements
  unsigned short* qh   = (unsigned short*)d_ws;      // fp16, 8 MB
  unsigned short* kh   = qh + N;                     // 8 MB
  unsigned short* vth  = kh + N;                     // 8 MB (transposed [bh][d][t])
  unsigned short* comb = vth + N;                    // 8 MB  (total 32 MB)

  dim3 g1(B_ * T_ / 64, H_, 3);
  qkv_kernel<<<g1, dim3(256), 0, stream>>>(x, Wq, Wk, Wv, qh, kh, vth);

  dim3 g2(T_ / 64, H_, B_);
  attn_kernel<<<g2, dim3(256), 0, stream>>>(qh, kh, vth, comb);

  dim3 g3(B_ * T_ / 64, E_ / 64);
  out_kernel<<<g3, dim3(256), 0, stream>>>(comb, Wo, x, out);
}

// Round 5
// 515.890 us; speedup vs baseline: 6.2986x; 1.6067x over previous
//
#include <hip/hip_runtime.h>
#include <hip/hip_bf16.h>

// MultiAttentionHead: B=2, T=2048, E=1024, H=16, D=64
// Inputs (fp32): x[B,T,E], Wq[H,E,D], Wk[H,E,D], Wv[H,E,D], Wo[E,E]
// Output (fp32): combined @ Wo + x   [B,T,E]
//
// ws layout (ushort=fp16 elements):
//   xh/comb : 0        .. 4M    (x fp16, later overwritten by attn output)
//   wt      : 4M       .. 7M    ([p][h][d][e] transposed QKV weights)
//   wot     : 7M       .. 8M    ([j][e] transposed Wo)
//   q       : 8M  k : 12M  vt : 16M .. 20M   (total 40 MB)

#define B_ 2
#define T_ 2048
#define E_ 1024
#define H_ 16
#define D_ 64

typedef _Float16 h8 __attribute__((ext_vector_type(8)));
typedef float f32x4 __attribute__((ext_vector_type(4)));

union U4 { uint4 u; h8 h; };

__device__ __forceinline__ float h2f(unsigned short s) {
  _Float16 h;
  __builtin_memcpy(&h, &s, 2);
  return (float)h;
}

__device__ __forceinline__ unsigned short f2h(float f) {
  _Float16 h = (_Float16)f;
  unsigned short s;
  __builtin_memcpy(&s, &h, 2);
  return s;
}

// ---------------------------------------------------------------------------
// Prep 0: x fp32 -> fp16.  grid = B*T*E/1024, block=256.
// ---------------------------------------------------------------------------
__global__ __launch_bounds__(256) void cvt_x(const float* __restrict__ x,
                                             unsigned short* __restrict__ xh) {
  const size_t i = ((size_t)blockIdx.x * 256 + threadIdx.x) * 4;
  const float4 f = *(const float4*)(x + i);
  ushort4 pk;
  pk.x = f2h(f.x); pk.y = f2h(f.y); pk.z = f2h(f.z); pk.w = f2h(f.w);
  *(ushort4*)(xh + i) = pk;
}

// ---------------------------------------------------------------------------
// Prep 1: Wq/Wk/Wv [h][e][d] fp32 -> wt [p][h][d][e] fp16. grid=(16,16,3).
// ---------------------------------------------------------------------------
__global__ __launch_bounds__(256) void tconv_w(
    const float* __restrict__ Wq, const float* __restrict__ Wk,
    const float* __restrict__ Wv, unsigned short* __restrict__ wt) {
  __shared__ float ts[64][65];
  const int p = blockIdx.z, h = blockIdx.y;
  const float* src = ((p == 0) ? Wq : (p == 1) ? Wk : Wv) + (size_t)h * E_ * D_;
  unsigned short* dst = wt + (size_t)(p * H_ + h) * D_ * E_;
  const int r0 = blockIdx.x * 64;  // e-tile
  const int lr = threadIdx.x >> 4, lc = (threadIdx.x & 15) * 4;
#pragma unroll
  for (int it = 0; it < 4; it++) {
    const float4 f = *(const float4*)(src + (size_t)(r0 + lr + it * 16) * D_ + lc);
    ts[lr + it * 16][lc] = f.x; ts[lr + it * 16][lc + 1] = f.y;
    ts[lr + it * 16][lc + 2] = f.z; ts[lr + it * 16][lc + 3] = f.w;
  }
  __syncthreads();
#pragma unroll
  for (int it = 0; it < 4; it++) {
    const int dr = lr + it * 16;  // d
    ushort4 pk;
    pk.x = f2h(ts[lc + 0][dr]); pk.y = f2h(ts[lc + 1][dr]);
    pk.z = f2h(ts[lc + 2][dr]); pk.w = f2h(ts[lc + 3][dr]);
    *(ushort4*)(dst + (size_t)dr * E_ + r0 + lc) = pk;
  }
}

// ---------------------------------------------------------------------------
// Prep 2: Wo [e][j] fp32 -> wot [j][e] fp16. grid=(16,16).
// ---------------------------------------------------------------------------
__global__ __launch_bounds__(256) void tconv_wo(const float* __restrict__ Wo,
                                                unsigned short* __restrict__ wot) {
  __shared__ float ts[64][65];
  const int r0 = blockIdx.x * 64;  // e-tile
  const int c0 = blockIdx.y * 64;  // j-tile
  const int lr = threadIdx.x >> 4, lc = (threadIdx.x & 15) * 4;
#pragma unroll
  for (int it = 0; it < 4; it++) {
    const float4 f = *(const float4*)(Wo + (size_t)(r0 + lr + it * 16) * E_ + c0 + lc);
    ts[lr + it * 16][lc] = f.x; ts[lr + it * 16][lc + 1] = f.y;
    ts[lr + it * 16][lc + 2] = f.z; ts[lr + it * 16][lc + 3] = f.w;
  }
  __syncthreads();
#pragma unroll
  for (int it = 0; it < 4; it++) {
    const int dr = lr + it * 16;  // j within tile
    ushort4 pk;
    pk.x = f2h(ts[lc + 0][dr]); pk.y = f2h(ts[lc + 1][dr]);
    pk.z = f2h(ts[lc + 2][dr]); pk.w = f2h(ts[lc + 3][dr]);
    *(ushort4*)(wot + (size_t)(c0 + dr) * E_ + r0 + lc) = pk;
  }
}

// ---------------------------------------------------------------------------
// Kernel 1: QKV projections via MFMA.  grid=(B*T/128, H, 3), block=256.
// Wave = 32 tokens x 64 outs; A/B frags are direct 16B global loads
// (xh rows and wt rows are both e-contiguous). q/k repacked row-major via
// per-wave LDS; v stored transposed [d][t] directly from C-layout.
// ---------------------------------------------------------------------------
__global__ __launch_bounds__(256) void qkv_mfma(
    const unsigned short* __restrict__ xh, const unsigned short* __restrict__ wt,
    unsigned short* __restrict__ qo, unsigned short* __restrict__ ko,
    unsigned short* __restrict__ vo)
{
  __shared__ unsigned short Cl[4][32 * 72];  // per-wave repack tile

  const int w = threadIdx.x >> 6, lane = threadIdx.x & 63;
  const int m16 = lane & 15, quad = lane >> 4;
  const int h = blockIdx.y, p = blockIdx.z;
  const int n0 = blockIdx.x * 128 + w * 32;  // wave's first token row
  const unsigned short* wb = wt + (size_t)(p * H_ + h) * D_ * E_;

  f32x4 acc[2][4];
#pragma unroll
  for (int rt = 0; rt < 2; rt++)
#pragma unroll
    for (int ct = 0; ct < 4; ct++) acc[rt][ct] = (f32x4){0.f, 0.f, 0.f, 0.f};

  for (int e0 = 0; e0 < E_; e0 += 32) {
    U4 a0, a1, bf[4];
    a0.u = *(const uint4*)(xh + (size_t)(n0 + m16) * E_ + e0 + quad * 8);
    a1.u = *(const uint4*)(xh + (size_t)(n0 + 16 + m16) * E_ + e0 + quad * 8);
#pragma unroll
    for (int ct = 0; ct < 4; ct++)
      bf[ct].u = *(const uint4*)(wb + (size_t)(ct * 16 + m16) * E_ + e0 + quad * 8);
#pragma unroll
    for (int ct = 0; ct < 4; ct++) {
      acc[0][ct] = __builtin_amdgcn_mfma_f32_16x16x32_f16(a0.h, bf[ct].h, acc[0][ct], 0, 0, 0);
      acc[1][ct] = __builtin_amdgcn_mfma_f32_16x16x32_f16(a1.h, bf[ct].h, acc[1][ct], 0, 0, 0);
    }
  }

  const int b  = (blockIdx.x * 128) >> 11;  // batch (128 | 2048, never straddles)
  const int t0 = n0 & (T_ - 1);
  const size_t bh = (size_t)(b * H_ + h);

  if (p == 2) {
    // vt[bh][d][t]: lane holds col d = ct*16+m16, rows quad*4+r = consecutive t
#pragma unroll
    for (int rt = 0; rt < 2; rt++)
#pragma unroll
      for (int ct = 0; ct < 4; ct++) {
        const int d = ct * 16 + m16;
        const int t = t0 + rt * 16 + quad * 4;
        ushort4 pk;
        pk.x = f2h(acc[rt][ct][0]); pk.y = f2h(acc[rt][ct][1]);
        pk.z = f2h(acc[rt][ct][2]); pk.w = f2h(acc[rt][ct][3]);
        *(ushort4*)(vo + (bh * D_ + d) * T_ + t) = pk;
      }
  } else {
    unsigned short* outp = (p == 0) ? qo : ko;
    unsigned short* Cw = &Cl[w][0];
#pragma unroll
    for (int rt = 0; rt < 2; rt++)
#pragma unroll
      for (int ct = 0; ct < 4; ct++)
#pragma unroll
        for (int r = 0; r < 4; r++)
          Cw[(rt * 16 + quad * 4 + r) * 72 + ct * 16 + m16] = f2h(acc[rt][ct][r]);
    // same-wave LDS: no barrier needed
    const int row = lane >> 1;
    const int half = (lane & 1) * 32;
    const uint4 d0 = *(const uint4*)(Cw + row * 72 + half);
    const uint4 d1 = *(const uint4*)(Cw + row * 72 + half + 8);
    const uint4 d2 = *(const uint4*)(Cw + row * 72 + half + 16);
    const uint4 d3 = *(const uint4*)(Cw + row * 72 + half + 24);
    unsigned short* dst = outp + (bh * T_ + t0 + row) * D_ + half;
    *(uint4*)(dst)      = d0;
    *(uint4*)(dst + 8)  = d1;
    *(uint4*)(dst + 16) = d2;
    *(uint4*)(dst + 24) = d3;
  }
}

// ---------------------------------------------------------------------------
// Kernel 2: MFMA flash attention (unchanged from round 4 — verified).
// grid=(T/64, H, B), block=256 (4 waves).
// ---------------------------------------------------------------------------
__global__ __launch_bounds__(256) void attn_kernel(
    const unsigned short* __restrict__ q, const unsigned short* __restrict__ k,
    const unsigned short* __restrict__ vt, unsigned short* __restrict__ comb)
{
  __shared__ unsigned short Pl[4][16 * 40];

  const int w    = threadIdx.x >> 6;
  const int lane = threadIdx.x & 63;
  const int m16  = lane & 15;
  const int quad = lane >> 4;
  const int h = blockIdx.y, b = blockIdx.z;
  const size_t bh = (size_t)(b * H_ + h);
  const int q0 = blockIdx.x * 64 + w * 16;

  U4 aQ0, aQ1;
  {
    const unsigned short* qrow = q + (bh * T_ + q0 + m16) * (size_t)D_;
    aQ0.u = *(const uint4*)(qrow + quad * 8);
    aQ1.u = *(const uint4*)(qrow + 32 + quad * 8);
  }

  f32x4 o0 = {0.f, 0.f, 0.f, 0.f}, o1 = o0, o2 = o0, o3 = o0;
  float mrow[4] = {-1e30f, -1e30f, -1e30f, -1e30f};
  float lrow[4] = {0.f, 0.f, 0.f, 0.f};

  const unsigned short* kb  = k  + bh * (size_t)(T_ * D_);
  const unsigned short* vtb = vt + bh * (size_t)(D_ * T_);
  unsigned short* Pw = &Pl[w][0];

  for (int kt = 0; kt < T_; kt += 32) {
    const unsigned short* kr0 = kb + (size_t)(kt + m16) * D_ + quad * 8;
    const unsigned short* kr1 = kb + (size_t)(kt + 16 + m16) * D_ + quad * 8;
    U4 b00, b01, b10, b11;
    b00.u = *(const uint4*)(kr0);
    b01.u = *(const uint4*)(kr0 + 32);
    b10.u = *(const uint4*)(kr1);
    b11.u = *(const uint4*)(kr1 + 32);

    U4 v0, v1, v2, v3;
    v0.u = *(const uint4*)(vtb + (size_t)(m16)      * T_ + kt + quad * 8);
    v1.u = *(const uint4*)(vtb + (size_t)(16 + m16) * T_ + kt + quad * 8);
    v2.u = *(const uint4*)(vtb + (size_t)(32 + m16) * T_ + kt + quad * 8);
    v3.u = *(const uint4*)(vtb + (size_t)(48 + m16) * T_ + kt + quad * 8);

    f32x4 s0 = {0.f, 0.f, 0.f, 0.f}, s1 = s0;
    s0 = __builtin_amdgcn_mfma_f32_16x16x32_f16(aQ0.h, b00.h, s0, 0, 0, 0);
    s0 = __builtin_amdgcn_mfma_f32_16x16x32_f16(aQ1.h, b01.h, s0, 0, 0, 0);
    s1 = __builtin_amdgcn_mfma_f32_16x16x32_f16(aQ0.h, b10.h, s1, 0, 0, 0);
    s1 = __builtin_amdgcn_mfma_f32_16x16x32_f16(aQ1.h, b11.h, s1, 0, 0, 0);

    float al[4];
#pragma unroll
    for (int r = 0; r < 4; r++) {
      const float sa = s0[r] * 0.125f;
      const float sb = s1[r] * 0.125f;
      float mt = fmaxf(sa, sb);
      mt = fmaxf(mt, __shfl_xor(mt, 1));
      mt = fmaxf(mt, __shfl_xor(mt, 2));
      mt = fmaxf(mt, __shfl_xor(mt, 4));
      mt = fmaxf(mt, __shfl_xor(mt, 8));
      const float mn = fmaxf(mrow[r], mt);
      const float a  = __expf(mrow[r] - mn);
      const float p0 = __expf(sa - mn);
      const float p1 = __expf(sb - mn);
      float rs = p0 + p1;
      rs += __shfl_xor(rs, 1);
      rs += __shfl_xor(rs, 2);
      rs += __shfl_xor(rs, 4);
      rs += __shfl_xor(rs, 8);
      lrow[r] = lrow[r] * a + rs;
      mrow[r] = mn;
      al[r] = a;
      Pw[(quad * 4 + r) * 40 + m16]      = f2h(p0);
      Pw[(quad * 4 + r) * 40 + 16 + m16] = f2h(p1);
    }

#pragma unroll
    for (int r = 0; r < 4; r++) {
      o0[r] *= al[r]; o1[r] *= al[r]; o2[r] *= al[r]; o3[r] *= al[r];
    }

    U4 aP;
    aP.u = *(const uint4*)(Pw + m16 * 40 + quad * 8);

    o0 = __builtin_amdgcn_mfma_f32_16x16x32_f16(aP.h, v0.h, o0, 0, 0, 0);
    o1 = __builtin_amdgcn_mfma_f32_16x16x32_f16(aP.h, v1.h, o1, 0, 0, 0);
    o2 = __builtin_amdgcn_mfma_f32_16x16x32_f16(aP.h, v2.h, o2, 0, 0, 0);
    o3 = __builtin_amdgcn_mfma_f32_16x16x32_f16(aP.h, v3.h, o3, 0, 0, 0);
  }

#pragma unroll
  for (int r = 0; r < 4; r++) {
    const float inv = 1.f / lrow[r];
    const int t = q0 + quad * 4 + r;
    unsigned short* dst = comb + ((size_t)b * T_ + t) * E_ + h * D_;
    dst[m16]      = f2h(o0[r] * inv);
    dst[16 + m16] = f2h(o1[r] * inv);
    dst[32 + m16] = f2h(o2[r] * inv);
    dst[48 + m16] = f2h(o3[r] * inv);
  }
}

// ---------------------------------------------------------------------------
// Kernel 3: out = comb @ Wo + x via MFMA.  grid=(B*T/128, E/64), block=256.
// ---------------------------------------------------------------------------
__global__ __launch_bounds__(256) void out_mfma(
    const unsigned short* __restrict__ comb, const unsigned short* __restrict__ wot,
    const float* __restrict__ x, float* __restrict__ out)
{
  const int w = threadIdx.x >> 6, lane = threadIdx.x & 63;
  const int m16 = lane & 15, quad = lane >> 4;
  const int n0 = blockIdx.x * 128 + w * 32;
  const int j0 = blockIdx.y * 64;

  f32x4 acc[2][4];
#pragma unroll
  for (int rt = 0; rt < 2; rt++)
#pragma unroll
    for (int ct = 0; ct < 4; ct++) acc[rt][ct] = (f32x4){0.f, 0.f, 0.f, 0.f};

  for (int e0 = 0; e0 < E_; e0 += 32) {
    U4 a0, a1, bf[4];
    a0.u = *(const uint4*)(comb + (size_t)(n0 + m16) * E_ + e0 + quad * 8);
    a1.u = *(const uint4*)(comb + (size_t)(n0 + 16 + m16) * E_ + e0 + quad * 8);
#pragma unroll
    for (int ct = 0; ct < 4; ct++)
      bf[ct].u = *(const uint4*)(wot + (size_t)(j0 + ct * 16 + m16) * E_ + e0 + quad * 8);
#pragma unroll
    for (int ct = 0; ct < 4; ct++) {
      acc[0][ct] = __builtin_amdgcn_mfma_f32_16x16x32_f16(a0.h, bf[ct].h, acc[0][ct], 0, 0, 0);
      acc[1][ct] = __builtin_amdgcn_mfma_f32_16x16x32_f16(a1.h, bf[ct].h, acc[1][ct], 0, 0, 0);
    }
  }

#pragma unroll
  for (int rt = 0; rt < 2; rt++)
#pragma unroll
    for (int r = 0; r < 4; r++) {
      const int n = n0 + rt * 16 + quad * 4 + r;
      const float* xr = x + (size_t)n * E_ + j0;
      float* orow = out + (size_t)n * E_ + j0;
#pragma unroll
      for (int ct = 0; ct < 4; ct++) {
        const int j = ct * 16 + m16;
        orow[j] = acc[rt][ct][r] + xr[j];
      }
    }
}

// ---------------------------------------------------------------------------
extern "C" void kernel_launch(void* const* d_in, const int* in_sizes, int n_in,
                              void* d_out, int out_size, void* d_ws, size_t ws_size,
                              hipStream_t stream) {
  (void)in_sizes; (void)n_in; (void)out_size; (void)ws_size;

  const float* x  = (const float*)d_in[0];
  const float* Wq = (const float*)d_in[1];
  const float* Wk = (const float*)d_in[2];
  const float* Wv = (const float*)d_in[3];
  const float* Wo = (const float*)d_in[4];
  float* out = (float*)d_out;

  unsigned short* ws0  = (unsigned short*)d_ws;
  unsigned short* xh   = ws0;                    // 4M elems (aliases comb)
  unsigned short* wt   = ws0 + 4194304;          // 3M
  unsigned short* wot  = ws0 + 7340032;          // 1M
  unsigned short* qh   = ws0 + 8388608;          // 4M
  unsigned short* kh   = ws0 + 12582912;         // 4M
  unsigned short* vth  = ws0 + 16777216;         // 4M   (total 40 MB)
  unsigned short* comb = xh;                     // alias: xh dead after qkv

  cvt_x<<<dim3(B_ * T_ * E_ / 1024), dim3(256), 0, stream>>>(x, xh);
  tconv_w<<<dim3(E_ / 64, H_, 3), dim3(256), 0, stream>>>(Wq, Wk, Wv, wt);
  tconv_wo<<<dim3(E_ / 64, E_ / 64), dim3(256), 0, stream>>>(Wo, wot);

  qkv_mfma<<<dim3(B_ * T_ / 128, H_, 3), dim3(256), 0, stream>>>(xh, wt, qh, kh, vth);

  attn_kernel<<<dim3(T_ / 64, H_, B_), dim3(256), 0, stream>>>(qh, kh, vth, comb);

  out_mfma<<<dim3(B_ * T_ / 128, E_ / 64), dim3(256), 0, stream>>>(comb, wot, x, out);
}

// Round 7
// 513.955 us; speedup vs baseline: 6.3223x; 1.0038x over previous
//
#include <hip/hip_runtime.h>
#include <hip/hip_bf16.h>

// MultiAttentionHead: B=2, T=2048, E=1024, H=16, D=64
// Inputs (fp32): x[B,T,E], Wq[H,E,D], Wk[H,E,D], Wv[H,E,D], Wo[E,E]
// Output (fp32): combined @ Wo + x   [B,T,E]
//
// ws layout (ushort=fp16 elements):
//   xh/comb : 0        .. 4M    (x fp16, later overwritten by attn output)
//   wt      : 4M       .. 7M    ([p][h][d][e] transposed QKV weights)
//   wot     : 7M       .. 8M    ([j][e] transposed Wo)
//   q       : 8M  k : 12M  vt : 16M .. 20M   (total 40 MB)

#define B_ 2
#define T_ 2048
#define E_ 1024
#define H_ 16
#define D_ 64

typedef _Float16 h8 __attribute__((ext_vector_type(8)));
typedef float f32x4 __attribute__((ext_vector_type(4)));

union U4 { uint4 u; h8 h; };

__device__ __forceinline__ float h2f(unsigned short s) {
  _Float16 h;
  __builtin_memcpy(&h, &s, 2);
  return (float)h;
}

__device__ __forceinline__ unsigned short f2h(float f) {
  _Float16 h = (_Float16)f;
  unsigned short s;
  __builtin_memcpy(&s, &h, 2);
  return s;
}

// ---------------------------------------------------------------------------
// Prep 0: x fp32 -> fp16.  grid = B*T*E/1024, block=256.
// ---------------------------------------------------------------------------
__global__ __launch_bounds__(256) void cvt_x(const float* __restrict__ x,
                                             unsigned short* __restrict__ xh) {
  const size_t i = ((size_t)blockIdx.x * 256 + threadIdx.x) * 4;
  const float4 f = *(const float4*)(x + i);
  ushort4 pk;
  pk.x = f2h(f.x); pk.y = f2h(f.y); pk.z = f2h(f.z); pk.w = f2h(f.w);
  *(ushort4*)(xh + i) = pk;
}

// ---------------------------------------------------------------------------
// Prep 1: Wq/Wk/Wv [h][e][d] fp32 -> wt [p][h][d][e] fp16. grid=(16,16,3).
// ---------------------------------------------------------------------------
__global__ __launch_bounds__(256) void tconv_w(
    const float* __restrict__ Wq, const float* __restrict__ Wk,
    const float* __restrict__ Wv, unsigned short* __restrict__ wt) {
  __shared__ float ts[64][65];
  const int p = blockIdx.z, h = blockIdx.y;
  const float* src = ((p == 0) ? Wq : (p == 1) ? Wk : Wv) + (size_t)h * E_ * D_;
  unsigned short* dst = wt + (size_t)(p * H_ + h) * D_ * E_;
  const int r0 = blockIdx.x * 64;  // e-tile
  const int lr = threadIdx.x >> 4, lc = (threadIdx.x & 15) * 4;
#pragma unroll
  for (int it = 0; it < 4; it++) {
    const float4 f = *(const float4*)(src + (size_t)(r0 + lr + it * 16) * D_ + lc);
    ts[lr + it * 16][lc] = f.x; ts[lr + it * 16][lc + 1] = f.y;
    ts[lr + it * 16][lc + 2] = f.z; ts[lr + it * 16][lc + 3] = f.w;
  }
  __syncthreads();
#pragma unroll
  for (int it = 0; it < 4; it++) {
    const int dr = lr + it * 16;  // d
    ushort4 pk;
    pk.x = f2h(ts[lc + 0][dr]); pk.y = f2h(ts[lc + 1][dr]);
    pk.z = f2h(ts[lc + 2][dr]); pk.w = f2h(ts[lc + 3][dr]);
    *(ushort4*)(dst + (size_t)dr * E_ + r0 + lc) = pk;
  }
}

// ---------------------------------------------------------------------------
// Prep 2: Wo [e][j] fp32 -> wot [j][e] fp16. grid=(16,16).
// ---------------------------------------------------------------------------
__global__ __launch_bounds__(256) void tconv_wo(const float* __restrict__ Wo,
                                                unsigned short* __restrict__ wot) {
  __shared__ float ts[64][65];
  const int r0 = blockIdx.x * 64;  // e-tile
  const int c0 = blockIdx.y * 64;  // j-tile
  const int lr = threadIdx.x >> 4, lc = (threadIdx.x & 15) * 4;
#pragma unroll
  for (int it = 0; it < 4; it++) {
    const float4 f = *(const float4*)(Wo + (size_t)(r0 + lr + it * 16) * E_ + c0 + lc);
    ts[lr + it * 16][lc] = f.x; ts[lr + it * 16][lc + 1] = f.y;
    ts[lr + it * 16][lc + 2] = f.z; ts[lr + it * 16][lc + 3] = f.w;
  }
  __syncthreads();
#pragma unroll
  for (int it = 0; it < 4; it++) {
    const int dr = lr + it * 16;  // j within tile
    ushort4 pk;
    pk.x = f2h(ts[lc + 0][dr]); pk.y = f2h(ts[lc + 1][dr]);
    pk.z = f2h(ts[lc + 2][dr]); pk.w = f2h(ts[lc + 3][dr]);
    *(ushort4*)(wot + (size_t)(c0 + dr) * E_ + r0 + lc) = pk;
  }
}

// ---------------------------------------------------------------------------
// Kernel 1: QKV projections via MFMA.  grid=(B*T/128, H, 3), block=256.
// (unchanged from round 5 — validated)
// ---------------------------------------------------------------------------
__global__ __launch_bounds__(256) void qkv_mfma(
    const unsigned short* __restrict__ xh, const unsigned short* __restrict__ wt,
    unsigned short* __restrict__ qo, unsigned short* __restrict__ ko,
    unsigned short* __restrict__ vo)
{
  __shared__ unsigned short Cl[4][32 * 72];  // per-wave repack tile

  const int w = threadIdx.x >> 6, lane = threadIdx.x & 63;
  const int m16 = lane & 15, quad = lane >> 4;
  const int h = blockIdx.y, p = blockIdx.z;
  const int n0 = blockIdx.x * 128 + w * 32;  // wave's first token row
  const unsigned short* wb = wt + (size_t)(p * H_ + h) * D_ * E_;

  f32x4 acc[2][4];
#pragma unroll
  for (int rt = 0; rt < 2; rt++)
#pragma unroll
    for (int ct = 0; ct < 4; ct++) acc[rt][ct] = (f32x4){0.f, 0.f, 0.f, 0.f};

  for (int e0 = 0; e0 < E_; e0 += 32) {
    U4 a0, a1, bf[4];
    a0.u = *(const uint4*)(xh + (size_t)(n0 + m16) * E_ + e0 + quad * 8);
    a1.u = *(const uint4*)(xh + (size_t)(n0 + 16 + m16) * E_ + e0 + quad * 8);
#pragma unroll
    for (int ct = 0; ct < 4; ct++)
      bf[ct].u = *(const uint4*)(wb + (size_t)(ct * 16 + m16) * E_ + e0 + quad * 8);
#pragma unroll
    for (int ct = 0; ct < 4; ct++) {
      acc[0][ct] = __builtin_amdgcn_mfma_f32_16x16x32_f16(a0.h, bf[ct].h, acc[0][ct], 0, 0, 0);
      acc[1][ct] = __builtin_amdgcn_mfma_f32_16x16x32_f16(a1.h, bf[ct].h, acc[1][ct], 0, 0, 0);
    }
  }

  const int b  = (blockIdx.x * 128) >> 11;  // batch (128 | 2048, never straddles)
  const int t0 = n0 & (T_ - 1);
  const size_t bh = (size_t)(b * H_ + h);

  if (p == 2) {
#pragma unroll
    for (int rt = 0; rt < 2; rt++)
#pragma unroll
      for (int ct = 0; ct < 4; ct++) {
        const int d = ct * 16 + m16;
        const int t = t0 + rt * 16 + quad * 4;
        ushort4 pk;
        pk.x = f2h(acc[rt][ct][0]); pk.y = f2h(acc[rt][ct][1]);
        pk.z = f2h(acc[rt][ct][2]); pk.w = f2h(acc[rt][ct][3]);
        *(ushort4*)(vo + (bh * D_ + d) * T_ + t) = pk;
      }
  } else {
    unsigned short* outp = (p == 0) ? qo : ko;
    unsigned short* Cw = &Cl[w][0];
#pragma unroll
    for (int rt = 0; rt < 2; rt++)
#pragma unroll
      for (int ct = 0; ct < 4; ct++)
#pragma unroll
        for (int r = 0; r < 4; r++)
          Cw[(rt * 16 + quad * 4 + r) * 72 + ct * 16 + m16] = f2h(acc[rt][ct][r]);
    const int row = lane >> 1;
    const int half = (lane & 1) * 32;
    const uint4 d0 = *(const uint4*)(Cw + row * 72 + half);
    const uint4 d1 = *(const uint4*)(Cw + row * 72 + half + 8);
    const uint4 d2 = *(const uint4*)(Cw + row * 72 + half + 16);
    const uint4 d3 = *(const uint4*)(Cw + row * 72 + half + 24);
    unsigned short* dst = outp + (bh * T_ + t0 + row) * D_ + half;
    *(uint4*)(dst)      = d0;
    *(uint4*)(dst + 8)  = d1;
    *(uint4*)(dst + 16) = d2;
    *(uint4*)(dst + 24) = d3;
  }
}

// ---------------------------------------------------------------------------
// Kernel 2: MFMA flash attention, key-parallel split.
// grid=(T/32, H, B), block=256 (4 waves = 2 pairs).
// Pair p handles 16 Q-rows; its two waves process even/odd 32-key chunks
// with the EXACT round-5 inner loop (shfl softmax, P via per-wave LDS).
// Barrier-protected flash merge in the epilogue combines the two partials.
// ---------------------------------------------------------------------------
__global__ __launch_bounds__(256) void attn_kernel(
    const unsigned short* __restrict__ q, const unsigned short* __restrict__ k,
    const unsigned short* __restrict__ vt, unsigned short* __restrict__ comb)
{
  __shared__ unsigned short Pl[4][16 * 40];
  __shared__ _Float16 Om[2][2][16][66];   // [pair][kpar][row][col] (pad 66)
  __shared__ float Ml[2][2][2][16];       // [pair][kpar][{m,l}][row]

  const int w    = threadIdx.x >> 6;
  const int lane = threadIdx.x & 63;
  const int m16  = lane & 15;
  const int quad = lane >> 4;
  const int pair = w >> 1;   // which 16-row Q tile in this block
  const int kpar = w & 1;    // even/odd 32-key chunks
  const int h = blockIdx.y, b = blockIdx.z;
  const size_t bh = (size_t)(b * H_ + h);
  const int q0 = blockIdx.x * 32 + pair * 16;

  // preload Q A-frags (two K=32 halves of D=64)
  U4 aQ0, aQ1;
  {
    const unsigned short* qrow = q + (bh * T_ + q0 + m16) * (size_t)D_;
    aQ0.u = *(const uint4*)(qrow + quad * 8);
    aQ1.u = *(const uint4*)(qrow + 32 + quad * 8);
  }

  f32x4 o0 = {0.f, 0.f, 0.f, 0.f}, o1 = o0, o2 = o0, o3 = o0;
  float mrow[4] = {-1e30f, -1e30f, -1e30f, -1e30f};
  float lrow[4] = {0.f, 0.f, 0.f, 0.f};

  const unsigned short* kb  = k  + bh * (size_t)(T_ * D_);
  const unsigned short* vtb = vt + bh * (size_t)(D_ * T_);
  unsigned short* Pw = &Pl[w][0];

  for (int kt = kpar * 32; kt < T_; kt += 64) {
    const unsigned short* kr0 = kb + (size_t)(kt + m16) * D_ + quad * 8;
    const unsigned short* kr1 = kb + (size_t)(kt + 16 + m16) * D_ + quad * 8;
    U4 b00, b01, b10, b11;
    b00.u = *(const uint4*)(kr0);
    b01.u = *(const uint4*)(kr0 + 32);
    b10.u = *(const uint4*)(kr1);
    b11.u = *(const uint4*)(kr1 + 32);

    U4 v0, v1, v2, v3;
    v0.u = *(const uint4*)(vtb + (size_t)(m16)      * T_ + kt + quad * 8);
    v1.u = *(const uint4*)(vtb + (size_t)(16 + m16) * T_ + kt + quad * 8);
    v2.u = *(const uint4*)(vtb + (size_t)(32 + m16) * T_ + kt + quad * 8);
    v3.u = *(const uint4*)(vtb + (size_t)(48 + m16) * T_ + kt + quad * 8);

    f32x4 s0 = {0.f, 0.f, 0.f, 0.f}, s1 = s0;
    s0 = __builtin_amdgcn_mfma_f32_16x16x32_f16(aQ0.h, b00.h, s0, 0, 0, 0);
    s0 = __builtin_amdgcn_mfma_f32_16x16x32_f16(aQ1.h, b01.h, s0, 0, 0, 0);
    s1 = __builtin_amdgcn_mfma_f32_16x16x32_f16(aQ0.h, b10.h, s1, 0, 0, 0);
    s1 = __builtin_amdgcn_mfma_f32_16x16x32_f16(aQ1.h, b11.h, s1, 0, 0, 0);

    float al[4];
#pragma unroll
    for (int r = 0; r < 4; r++) {
      const float sa = s0[r] * 0.125f;   // 1/sqrt(64)
      const float sb = s1[r] * 0.125f;
      float mt = fmaxf(sa, sb);
      mt = fmaxf(mt, __shfl_xor(mt, 1));
      mt = fmaxf(mt, __shfl_xor(mt, 2));
      mt = fmaxf(mt, __shfl_xor(mt, 4));
      mt = fmaxf(mt, __shfl_xor(mt, 8));
      const float mn = fmaxf(mrow[r], mt);
      const float a  = __expf(mrow[r] - mn);
      const float p0 = __expf(sa - mn);
      const float p1 = __expf(sb - mn);
      float rs = p0 + p1;
      rs += __shfl_xor(rs, 1);
      rs += __shfl_xor(rs, 2);
      rs += __shfl_xor(rs, 4);
      rs += __shfl_xor(rs, 8);
      lrow[r] = lrow[r] * a + rs;
      mrow[r] = mn;
      al[r] = a;
      Pw[(quad * 4 + r) * 40 + m16]      = f2h(p0);
      Pw[(quad * 4 + r) * 40 + 16 + m16] = f2h(p1);
    }

#pragma unroll
    for (int r = 0; r < 4; r++) {
      o0[r] *= al[r]; o1[r] *= al[r]; o2[r] *= al[r]; o3[r] *= al[r];
    }

    U4 aP;
    aP.u = *(const uint4*)(Pw + m16 * 40 + quad * 8);

    o0 = __builtin_amdgcn_mfma_f32_16x16x32_f16(aP.h, v0.h, o0, 0, 0, 0);
    o1 = __builtin_amdgcn_mfma_f32_16x16x32_f16(aP.h, v1.h, o1, 0, 0, 0);
    o2 = __builtin_amdgcn_mfma_f32_16x16x32_f16(aP.h, v2.h, o2, 0, 0, 0);
    o3 = __builtin_amdgcn_mfma_f32_16x16x32_f16(aP.h, v3.h, o3, 0, 0, 0);
  }

  // ---- stage partial (m, l, O) ----
#pragma unroll
  for (int r = 0; r < 4; r++) {
    const int row = quad * 4 + r;
    Om[pair][kpar][row][m16]      = (_Float16)o0[r];
    Om[pair][kpar][row][16 + m16] = (_Float16)o1[r];
    Om[pair][kpar][row][32 + m16] = (_Float16)o2[r];
    Om[pair][kpar][row][48 + m16] = (_Float16)o3[r];
    if (m16 == 0) {   // m/l uniform across the 16-lane row group
      Ml[pair][kpar][0][row] = mrow[r];
      Ml[pair][kpar][1][row] = lrow[r];
    }
  }
  __syncthreads();

  // ---- flash merge: 128 lanes per pair, each handles 8 cols of one row ----
  const int idx = kpar * 64 + lane;  // 0..127 within the pair
  const int row = idx >> 3;          // 0..15
  const int c0  = (idx & 7) * 8;     // 0,8,...,56
  const float mA = Ml[pair][0][0][row], lA = Ml[pair][0][1][row];
  const float mB = Ml[pair][1][0][row], lB = Ml[pair][1][1][row];
  const float mS = fmaxf(mA, mB);
  const float aA = __expf(mA - mS);
  const float aB = __expf(mB - mS);
  const float inv = 1.f / (lA * aA + lB * aB);

  const int t = blockIdx.x * 32 + pair * 16 + row;
  unsigned short* dst = comb + ((size_t)b * T_ + t) * E_ + h * D_ + c0;
  union { uint4 u; unsigned short s[8]; } pk;
#pragma unroll
  for (int c = 0; c < 8; c++) {
    const float oA = (float)Om[pair][0][row][c0 + c];
    const float oB = (float)Om[pair][1][row][c0 + c];
    pk.s[c] = f2h((oA * aA + oB * aB) * inv);
  }
  *(uint4*)dst = pk.u;
}

// ---------------------------------------------------------------------------
// Kernel 3: out = comb @ Wo + x via MFMA.  grid=(B*T/128, E/64), block=256.
// (unchanged from round 5 — validated)
// ---------------------------------------------------------------------------
__global__ __launch_bounds__(256) void out_mfma(
    const unsigned short* __restrict__ comb, const unsigned short* __restrict__ wot,
    const float* __restrict__ x, float* __restrict__ out)
{
  const int w = threadIdx.x >> 6, lane = threadIdx.x & 63;
  const int m16 = lane & 15, quad = lane >> 4;
  const int n0 = blockIdx.x * 128 + w * 32;
  const int j0 = blockIdx.y * 64;

  f32x4 acc[2][4];
#pragma unroll
  for (int rt = 0; rt < 2; rt++)
#pragma unroll
    for (int ct = 0; ct < 4; ct++) acc[rt][ct] = (f32x4){0.f, 0.f, 0.f, 0.f};

  for (int e0 = 0; e0 < E_; e0 += 32) {
    U4 a0, a1, bf[4];
    a0.u = *(const uint4*)(comb + (size_t)(n0 + m16) * E_ + e0 + quad * 8);
    a1.u = *(const uint4*)(comb + (size_t)(n0 + 16 + m16) * E_ + e0 + quad * 8);
#pragma unroll
    for (int ct = 0; ct < 4; ct++)
      bf[ct].u = *(const uint4*)(wot + (size_t)(j0 + ct * 16 + m16) * E_ + e0 + quad * 8);
#pragma unroll
    for (int ct = 0; ct < 4; ct++) {
      acc[0][ct] = __builtin_amdgcn_mfma_f32_16x16x32_f16(a0.h, bf[ct].h, acc[0][ct], 0, 0, 0);
      acc[1][ct] = __builtin_amdgcn_mfma_f32_16x16x32_f16(a1.h, bf[ct].h, acc[1][ct], 0, 0, 0);
    }
  }

#pragma unroll
  for (int rt = 0; rt < 2; rt++)
#pragma unroll
    for (int r = 0; r < 4; r++) {
      const int n = n0 + rt * 16 + quad * 4 + r;
      const float* xr = x + (size_t)n * E_ + j0;
      float* orow = out + (size_t)n * E_ + j0;
#pragma unroll
      for (int ct = 0; ct < 4; ct++) {
        const int j = ct * 16 + m16;
        orow[j] = acc[rt][ct][r] + xr[j];
      }
    }
}

// ---------------------------------------------------------------------------
extern "C" void kernel_launch(void* const* d_in, const int* in_sizes, int n_in,
                              void* d_out, int out_size, void* d_ws, size_t ws_size,
                              hipStream_t stream) {
  (void)in_sizes; (void)n_in; (void)out_size; (void)ws_size;

  const float* x  = (const float*)d_in[0];
  const float* Wq = (const float*)d_in[1];
  const float* Wk = (const float*)d_in[2];
  const float* Wv = (const float*)d_in[3];
  const float* Wo = (const float*)d_in[4];
  float* out = (float*)d_out;

  unsigned short* ws0  = (unsigned short*)d_ws;
  unsigned short* xh   = ws0;                    // 4M elems (aliases comb)
  unsigned short* wt   = ws0 + 4194304;          // 3M
  unsigned short* wot  = ws0 + 7340032;          // 1M
  unsigned short* qh   = ws0 + 8388608;          // 4M
  unsigned short* kh   = ws0 + 12582912;         // 4M
  unsigned short* vth  = ws0 + 16777216;         // 4M   (total 40 MB)
  unsigned short* comb = xh;                     // alias: xh dead after qkv

  cvt_x<<<dim3(B_ * T_ * E_ / 1024), dim3(256), 0, stream>>>(x, xh);
  tconv_w<<<dim3(E_ / 64, H_, 3), dim3(256), 0, stream>>>(Wq, Wk, Wv, wt);
  tconv_wo<<<dim3(E_ / 64, E_ / 64), dim3(256), 0, stream>>>(Wo, wot);

  qkv_mfma<<<dim3(B_ * T_ / 128, H_, 3), dim3(256), 0, stream>>>(xh, wt, qh, kh, vth);

  attn_kernel<<<dim3(T_ / 32, H_, B_), dim3(256), 0, stream>>>(qh, kh, vth, comb);

  out_mfma<<<dim3(B_ * T_ / 128, E_ / 64), dim3(256), 0, stream>>>(comb, wot, x, out);
}

// Round 8
// 513.636 us; speedup vs baseline: 6.3262x; 1.0006x over previous
//
#include <hip/hip_runtime.h>
#include <hip/hip_bf16.h>

// MultiAttentionHead: B=2, T=2048, E=1024, H=16, D=64
// Inputs (fp32): x[B,T,E], Wq[H,E,D], Wk[H,E,D], Wv[H,E,D], Wo[E,E]
// Output (fp32): combined @ Wo + x   [B,T,E]
//
// ws layout (ushort=fp16 elements):
//   xh/comb : 0        .. 4M    (x fp16, later overwritten by attn output)
//   wt      : 4M       .. 7M    ([p][h][d][e] transposed QKV weights)
//   wot     : 7M       .. 8M    ([j][e] transposed Wo)
//   q       : 8M  k : 12M  vt : 16M .. 20M   (total 40 MB)

#define B_ 2
#define T_ 2048
#define E_ 1024
#define H_ 16
#define D_ 64

typedef _Float16 h8 __attribute__((ext_vector_type(8)));
typedef float f32x4 __attribute__((ext_vector_type(4)));

union U4 { uint4 u; h8 h; };

__device__ __forceinline__ float h2f(unsigned short s) {
  _Float16 h;
  __builtin_memcpy(&h, &s, 2);
  return (float)h;
}

__device__ __forceinline__ unsigned short f2h(float f) {
  _Float16 h = (_Float16)f;
  unsigned short s;
  __builtin_memcpy(&s, &h, 2);
  return s;
}

// DPP cross-lane move within a 16-lane row (full-rate VALU, no LDS pipe).
// Round-6 first-launch correctness validated these patterns bit-exactly.
template <int CTRL>
__device__ __forceinline__ float dppmv(float x) {
  union { float f; int i; } c;
  c.f = x;
  c.i = __builtin_amdgcn_mov_dpp(c.i, CTRL, 0xF, 0xF, true);
  return c.f;
}

__device__ __forceinline__ float rowmax16(float x) {
  x = fmaxf(x, dppmv<0xB1>(x));   // quad_perm(1,0,3,2): lane^1
  x = fmaxf(x, dppmv<0x4E>(x));   // quad_perm(2,3,0,1): lane^2
  x = fmaxf(x, dppmv<0x141>(x));  // row_half_mirror: 8-wide
  x = fmaxf(x, dppmv<0x140>(x));  // row_mirror: 16-wide
  return x;
}

__device__ __forceinline__ float rowsum16(float x) {
  x += dppmv<0xB1>(x);
  x += dppmv<0x4E>(x);
  x += dppmv<0x141>(x);
  x += dppmv<0x140>(x);
  return x;
}

// ---------------------------------------------------------------------------
// Prep 0: x fp32 -> fp16.  grid = B*T*E/1024, block=256.
// ---------------------------------------------------------------------------
__global__ __launch_bounds__(256) void cvt_x(const float* __restrict__ x,
                                             unsigned short* __restrict__ xh) {
  const size_t i = ((size_t)blockIdx.x * 256 + threadIdx.x) * 4;
  const float4 f = *(const float4*)(x + i);
  ushort4 pk;
  pk.x = f2h(f.x); pk.y = f2h(f.y); pk.z = f2h(f.z); pk.w = f2h(f.w);
  *(ushort4*)(xh + i) = pk;
}

// ---------------------------------------------------------------------------
// Prep 1: Wq/Wk/Wv [h][e][d] fp32 -> wt [p][h][d][e] fp16. grid=(16,16,3).
// ---------------------------------------------------------------------------
__global__ __launch_bounds__(256) void tconv_w(
    const float* __restrict__ Wq, const float* __restrict__ Wk,
    const float* __restrict__ Wv, unsigned short* __restrict__ wt) {
  __shared__ float ts[64][65];
  const int p = blockIdx.z, h = blockIdx.y;
  const float* src = ((p == 0) ? Wq : (p == 1) ? Wk : Wv) + (size_t)h * E_ * D_;
  unsigned short* dst = wt + (size_t)(p * H_ + h) * D_ * E_;
  const int r0 = blockIdx.x * 64;  // e-tile
  const int lr = threadIdx.x >> 4, lc = (threadIdx.x & 15) * 4;
#pragma unroll
  for (int it = 0; it < 4; it++) {
    const float4 f = *(const float4*)(src + (size_t)(r0 + lr + it * 16) * D_ + lc);
    ts[lr + it * 16][lc] = f.x; ts[lr + it * 16][lc + 1] = f.y;
    ts[lr + it * 16][lc + 2] = f.z; ts[lr + it * 16][lc + 3] = f.w;
  }
  __syncthreads();
#pragma unroll
  for (int it = 0; it < 4; it++) {
    const int dr = lr + it * 16;  // d
    ushort4 pk;
    pk.x = f2h(ts[lc + 0][dr]); pk.y = f2h(ts[lc + 1][dr]);
    pk.z = f2h(ts[lc + 2][dr]); pk.w = f2h(ts[lc + 3][dr]);
    *(ushort4*)(dst + (size_t)dr * E_ + r0 + lc) = pk;
  }
}

// ---------------------------------------------------------------------------
// Prep 2: Wo [e][j] fp32 -> wot [j][e] fp16. grid=(16,16).
// ---------------------------------------------------------------------------
__global__ __launch_bounds__(256) void tconv_wo(const float* __restrict__ Wo,
                                                unsigned short* __restrict__ wot) {
  __shared__ float ts[64][65];
  const int r0 = blockIdx.x * 64;  // e-tile
  const int c0 = blockIdx.y * 64;  // j-tile
  const int lr = threadIdx.x >> 4, lc = (threadIdx.x & 15) * 4;
#pragma unroll
  for (int it = 0; it < 4; it++) {
    const float4 f = *(const float4*)(Wo + (size_t)(r0 + lr + it * 16) * E_ + c0 + lc);
    ts[lr + it * 16][lc] = f.x; ts[lr + it * 16][lc + 1] = f.y;
    ts[lr + it * 16][lc + 2] = f.z; ts[lr + it * 16][lc + 3] = f.w;
  }
  __syncthreads();
#pragma unroll
  for (int it = 0; it < 4; it++) {
    const int dr = lr + it * 16;  // j within tile
    ushort4 pk;
    pk.x = f2h(ts[lc + 0][dr]); pk.y = f2h(ts[lc + 1][dr]);
    pk.z = f2h(ts[lc + 2][dr]); pk.w = f2h(ts[lc + 3][dr]);
    *(ushort4*)(wot + (size_t)(c0 + dr) * E_ + r0 + lc) = pk;
  }
}

// ---------------------------------------------------------------------------
// Kernel 1: QKV projections via MFMA.  grid=(B*T/128, H, 3), block=256.
// (validated)
// ---------------------------------------------------------------------------
__global__ __launch_bounds__(256) void qkv_mfma(
    const unsigned short* __restrict__ xh, const unsigned short* __restrict__ wt,
    unsigned short* __restrict__ qo, unsigned short* __restrict__ ko,
    unsigned short* __restrict__ vo)
{
  __shared__ unsigned short Cl[4][32 * 72];  // per-wave repack tile

  const int w = threadIdx.x >> 6, lane = threadIdx.x & 63;
  const int m16 = lane & 15, quad = lane >> 4;
  const int h = blockIdx.y, p = blockIdx.z;
  const int n0 = blockIdx.x * 128 + w * 32;  // wave's first token row
  const unsigned short* wb = wt + (size_t)(p * H_ + h) * D_ * E_;

  f32x4 acc[2][4];
#pragma unroll
  for (int rt = 0; rt < 2; rt++)
#pragma unroll
    for (int ct = 0; ct < 4; ct++) acc[rt][ct] = (f32x4){0.f, 0.f, 0.f, 0.f};

  for (int e0 = 0; e0 < E_; e0 += 32) {
    U4 a0, a1, bf[4];
    a0.u = *(const uint4*)(xh + (size_t)(n0 + m16) * E_ + e0 + quad * 8);
    a1.u = *(const uint4*)(xh + (size_t)(n0 + 16 + m16) * E_ + e0 + quad * 8);
#pragma unroll
    for (int ct = 0; ct < 4; ct++)
      bf[ct].u = *(const uint4*)(wb + (size_t)(ct * 16 + m16) * E_ + e0 + quad * 8);
#pragma unroll
    for (int ct = 0; ct < 4; ct++) {
      acc[0][ct] = __builtin_amdgcn_mfma_f32_16x16x32_f16(a0.h, bf[ct].h, acc[0][ct], 0, 0, 0);
      acc[1][ct] = __builtin_amdgcn_mfma_f32_16x16x32_f16(a1.h, bf[ct].h, acc[1][ct], 0, 0, 0);
    }
  }

  const int b  = (blockIdx.x * 128) >> 11;  // batch (128 | 2048, never straddles)
  const int t0 = n0 & (T_ - 1);
  const size_t bh = (size_t)(b * H_ + h);

  if (p == 2) {
#pragma unroll
    for (int rt = 0; rt < 2; rt++)
#pragma unroll
      for (int ct = 0; ct < 4; ct++) {
        const int d = ct * 16 + m16;
        const int t = t0 + rt * 16 + quad * 4;
        ushort4 pk;
        pk.x = f2h(acc[rt][ct][0]); pk.y = f2h(acc[rt][ct][1]);
        pk.z = f2h(acc[rt][ct][2]); pk.w = f2h(acc[rt][ct][3]);
        *(ushort4*)(vo + (bh * D_ + d) * T_ + t) = pk;
      }
  } else {
    unsigned short* outp = (p == 0) ? qo : ko;
    unsigned short* Cw = &Cl[w][0];
#pragma unroll
    for (int rt = 0; rt < 2; rt++)
#pragma unroll
      for (int ct = 0; ct < 4; ct++)
#pragma unroll
        for (int r = 0; r < 4; r++)
          Cw[(rt * 16 + quad * 4 + r) * 72 + ct * 16 + m16] = f2h(acc[rt][ct][r]);
    const int row = lane >> 1;
    const int half = (lane & 1) * 32;
    const uint4 d0 = *(const uint4*)(Cw + row * 72 + half);
    const uint4 d1 = *(const uint4*)(Cw + row * 72 + half + 8);
    const uint4 d2 = *(const uint4*)(Cw + row * 72 + half + 16);
    const uint4 d3 = *(const uint4*)(Cw + row * 72 + half + 24);
    unsigned short* dst = outp + (bh * T_ + t0 + row) * D_ + half;
    *(uint4*)(dst)      = d0;
    *(uint4*)(dst + 8)  = d1;
    *(uint4*)(dst + 16) = d2;
    *(uint4*)(dst + 24) = d3;
  }
}

// ---------------------------------------------------------------------------
// Kernel 2: MFMA flash attention, key-parallel split, DPP softmax.
// grid=(T/32, H, B), block=256 (4 waves = 2 pairs).
// ONLY change vs round 7: __shfl_xor reductions -> DPP reductions
// (rowmax16/rowsum16). Everything else byte-identical.
// ---------------------------------------------------------------------------
__global__ __launch_bounds__(256) void attn_kernel(
    const unsigned short* __restrict__ q, const unsigned short* __restrict__ k,
    const unsigned short* __restrict__ vt, unsigned short* __restrict__ comb)
{
  __shared__ unsigned short Pl[4][16 * 40];
  __shared__ _Float16 Om[2][2][16][66];   // [pair][kpar][row][col] (pad 66)
  __shared__ float Ml[2][2][2][16];       // [pair][kpar][{m,l}][row]

  const int w    = threadIdx.x >> 6;
  const int lane = threadIdx.x & 63;
  const int m16  = lane & 15;
  const int quad = lane >> 4;
  const int pair = w >> 1;   // which 16-row Q tile in this block
  const int kpar = w & 1;    // even/odd 32-key chunks
  const int h = blockIdx.y, b = blockIdx.z;
  const size_t bh = (size_t)(b * H_ + h);
  const int q0 = blockIdx.x * 32 + pair * 16;

  // preload Q A-frags (two K=32 halves of D=64)
  U4 aQ0, aQ1;
  {
    const unsigned short* qrow = q + (bh * T_ + q0 + m16) * (size_t)D_;
    aQ0.u = *(const uint4*)(qrow + quad * 8);
    aQ1.u = *(const uint4*)(qrow + 32 + quad * 8);
  }

  f32x4 o0 = {0.f, 0.f, 0.f, 0.f}, o1 = o0, o2 = o0, o3 = o0;
  float mrow[4] = {-1e30f, -1e30f, -1e30f, -1e30f};
  float lrow[4] = {0.f, 0.f, 0.f, 0.f};

  const unsigned short* kb  = k  + bh * (size_t)(T_ * D_);
  const unsigned short* vtb = vt + bh * (size_t)(D_ * T_);
  unsigned short* Pw = &Pl[w][0];

  for (int kt = kpar * 32; kt < T_; kt += 64) {
    const unsigned short* kr0 = kb + (size_t)(kt + m16) * D_ + quad * 8;
    const unsigned short* kr1 = kb + (size_t)(kt + 16 + m16) * D_ + quad * 8;
    U4 b00, b01, b10, b11;
    b00.u = *(const uint4*)(kr0);
    b01.u = *(const uint4*)(kr0 + 32);
    b10.u = *(const uint4*)(kr1);
    b11.u = *(const uint4*)(kr1 + 32);

    U4 v0, v1, v2, v3;
    v0.u = *(const uint4*)(vtb + (size_t)(m16)      * T_ + kt + quad * 8);
    v1.u = *(const uint4*)(vtb + (size_t)(16 + m16) * T_ + kt + quad * 8);
    v2.u = *(const uint4*)(vtb + (size_t)(32 + m16) * T_ + kt + quad * 8);
    v3.u = *(const uint4*)(vtb + (size_t)(48 + m16) * T_ + kt + quad * 8);

    f32x4 s0 = {0.f, 0.f, 0.f, 0.f}, s1 = s0;
    s0 = __builtin_amdgcn_mfma_f32_16x16x32_f16(aQ0.h, b00.h, s0, 0, 0, 0);
    s0 = __builtin_amdgcn_mfma_f32_16x16x32_f16(aQ1.h, b01.h, s0, 0, 0, 0);
    s1 = __builtin_amdgcn_mfma_f32_16x16x32_f16(aQ0.h, b10.h, s1, 0, 0, 0);
    s1 = __builtin_amdgcn_mfma_f32_16x16x32_f16(aQ1.h, b11.h, s1, 0, 0, 0);

    float al[4];
#pragma unroll
    for (int r = 0; r < 4; r++) {
      const float sa = s0[r] * 0.125f;   // 1/sqrt(64)
      const float sb = s1[r] * 0.125f;
      const float mt = rowmax16(fmaxf(sa, sb));
      const float mn = fmaxf(mrow[r], mt);
      const float a  = __expf(mrow[r] - mn);
      const float p0 = __expf(sa - mn);
      const float p1 = __expf(sb - mn);
      const float rs = rowsum16(p0 + p1);
      lrow[r] = lrow[r] * a + rs;
      mrow[r] = mn;
      al[r] = a;
      Pw[(quad * 4 + r) * 40 + m16]      = f2h(p0);
      Pw[(quad * 4 + r) * 40 + 16 + m16] = f2h(p1);
    }

#pragma unroll
    for (int r = 0; r < 4; r++) {
      o0[r] *= al[r]; o1[r] *= al[r]; o2[r] *= al[r]; o3[r] *= al[r];
    }

    U4 aP;
    aP.u = *(const uint4*)(Pw + m16 * 40 + quad * 8);

    o0 = __builtin_amdgcn_mfma_f32_16x16x32_f16(aP.h, v0.h, o0, 0, 0, 0);
    o1 = __builtin_amdgcn_mfma_f32_16x16x32_f16(aP.h, v1.h, o1, 0, 0, 0);
    o2 = __builtin_amdgcn_mfma_f32_16x16x32_f16(aP.h, v2.h, o2, 0, 0, 0);
    o3 = __builtin_amdgcn_mfma_f32_16x16x32_f16(aP.h, v3.h, o3, 0, 0, 0);
  }

  // ---- stage partial (m, l, O) ----
#pragma unroll
  for (int r = 0; r < 4; r++) {
    const int row = quad * 4 + r;
    Om[pair][kpar][row][m16]      = (_Float16)o0[r];
    Om[pair][kpar][row][16 + m16] = (_Float16)o1[r];
    Om[pair][kpar][row][32 + m16] = (_Float16)o2[r];
    Om[pair][kpar][row][48 + m16] = (_Float16)o3[r];
    if (m16 == 0) {   // m/l uniform across the 16-lane row group
      Ml[pair][kpar][0][row] = mrow[r];
      Ml[pair][kpar][1][row] = lrow[r];
    }
  }
  __syncthreads();

  // ---- flash merge: 128 lanes per pair, each handles 8 cols of one row ----
  const int idx = kpar * 64 + lane;  // 0..127 within the pair
  const int row = idx >> 3;          // 0..15
  const int c0  = (idx & 7) * 8;     // 0,8,...,56
  const float mA = Ml[pair][0][0][row], lA = Ml[pair][0][1][row];
  const float mB = Ml[pair][1][0][row], lB = Ml[pair][1][1][row];
  const float mS = fmaxf(mA, mB);
  const float aA = __expf(mA - mS);
  const float aB = __expf(mB - mS);
  const float inv = 1.f / (lA * aA + lB * aB);

  const int t = blockIdx.x * 32 + pair * 16 + row;
  unsigned short* dst = comb + ((size_t)b * T_ + t) * E_ + h * D_ + c0;
  union { uint4 u; unsigned short s[8]; } pk;
#pragma unroll
  for (int c = 0; c < 8; c++) {
    const float oA = (float)Om[pair][0][row][c0 + c];
    const float oB = (float)Om[pair][1][row][c0 + c];
    pk.s[c] = f2h((oA * aA + oB * aB) * inv);
  }
  *(uint4*)dst = pk.u;
}

// ---------------------------------------------------------------------------
// Kernel 3: out = comb @ Wo + x via MFMA.  grid=(B*T/128, E/64), block=256.
// (validated)
// ---------------------------------------------------------------------------
__global__ __launch_bounds__(256) void out_mfma(
    const unsigned short* __restrict__ comb, const unsigned short* __restrict__ wot,
    const float* __restrict__ x, float* __restrict__ out)
{
  const int w = threadIdx.x >> 6, lane = threadIdx.x & 63;
  const int m16 = lane & 15, quad = lane >> 4;
  const int n0 = blockIdx.x * 128 + w * 32;
  const int j0 = blockIdx.y * 64;

  f32x4 acc[2][4];
#pragma unroll
  for (int rt = 0; rt < 2; rt++)
#pragma unroll
    for (int ct = 0; ct < 4; ct++) acc[rt][ct] = (f32x4){0.f, 0.f, 0.f, 0.f};

  for (int e0 = 0; e0 < E_; e0 += 32) {
    U4 a0, a1, bf[4];
    a0.u = *(const uint4*)(comb + (size_t)(n0 + m16) * E_ + e0 + quad * 8);
    a1.u = *(const uint4*)(comb + (size_t)(n0 + 16 + m16) * E_ + e0 + quad * 8);
#pragma unroll
    for (int ct = 0; ct < 4; ct++)
      bf[ct].u = *(const uint4*)(wot + (size_t)(j0 + ct * 16 + m16) * E_ + e0 + quad * 8);
#pragma unroll
    for (int ct = 0; ct < 4; ct++) {
      acc[0][ct] = __builtin_amdgcn_mfma_f32_16x16x32_f16(a0.h, bf[ct].h, acc[0][ct], 0, 0, 0);
      acc[1][ct] = __builtin_amdgcn_mfma_f32_16x16x32_f16(a1.h, bf[ct].h, acc[1][ct], 0, 0, 0);
    }
  }

#pragma unroll
  for (int rt = 0; rt < 2; rt++)
#pragma unroll
    for (int r = 0; r < 4; r++) {
      const int n = n0 + rt * 16 + quad * 4 + r;
      const float* xr = x + (size_t)n * E_ + j0;
      float* orow = out + (size_t)n * E_ + j0;
#pragma unroll
      for (int ct = 0; ct < 4; ct++) {
        const int j = ct * 16 + m16;
        orow[j] = acc[rt][ct][r] + xr[j];
      }
    }
}

// ---------------------------------------------------------------------------
extern "C" void kernel_launch(void* const* d_in, const int* in_sizes, int n_in,
                              void* d_out, int out_size, void* d_ws, size_t ws_size,
                              hipStream_t stream) {
  (void)in_sizes; (void)n_in; (void)out_size; (void)ws_size;

  const float* x  = (const float*)d_in[0];
  const float* Wq = (const float*)d_in[1];
  const float* Wk = (const float*)d_in[2];
  const float* Wv = (const float*)d_in[3];
  const float* Wo = (const float*)d_in[4];
  float* out = (float*)d_out;

  unsigned short* ws0  = (unsigned short*)d_ws;
  unsigned short* xh   = ws0;                    // 4M elems (aliases comb)
  unsigned short* wt   = ws0 + 4194304;          // 3M
  unsigned short* wot  = ws0 + 7340032;          // 1M
  unsigned short* qh   = ws0 + 8388608;          // 4M
  unsigned short* kh   = ws0 + 12582912;         // 4M
  unsigned short* vth  = ws0 + 16777216;         // 4M   (total 40 MB)
  unsigned short* comb = xh;                     // alias: xh dead after qkv

  cvt_x<<<dim3(B_ * T_ * E_ / 1024), dim3(256), 0, stream>>>(x, xh);
  tconv_w<<<dim3(E_ / 64, H_, 3), dim3(256), 0, stream>>>(Wq, Wk, Wv, wt);
  tconv_wo<<<dim3(E_ / 64, E_ / 64), dim3(256), 0, stream>>>(Wo, wot);

  qkv_mfma<<<dim3(B_ * T_ / 128, H_, 3), dim3(256), 0, stream>>>(xh, wt, qh, kh, vth);

  attn_kernel<<<dim3(T_ / 32, H_, B_), dim3(256), 0, stream>>>(qh, kh, vth, comb);

  out_mfma<<<dim3(B_ * T_ / 128, E_ / 64), dim3(256), 0, stream>>>(comb, wot, x, out);
}